// Round 8
// baseline (305.315 us; speedup 1.0000x reference)
//
#include <hip/hip_runtime.h>
#include <hip/hip_fp16.h>

// ---------------------------------------------------------------------------
// GCN: per-call CSR build (LDS-binned two-phase partition, scan inlined),
// then 3x (MFMA-f16 GEMM -> CSR-SpMM). H fp8 e4m3 for layers 0/1, fp16 for
// layer 2. BN stats separate; BN finalize+affine+ReLU fused into next GEMM.
// R7 (proven, 294.9us): prep merged into partA; partB merged with gemm0
// (block-range split + smem overlay); stats zero via hipMemsetAsync.
// R8 changes (independent mechanisms, all low-risk):
//   - CG_N 8->16 (CG_SHIFT 12): 2x finer per-row column sort -> concurrent
//     waves' phased gather working set ~1MB/group, L2-resident (gather
//     locality was the remaining SpMM lever; instr-width exhausted R4/R6).
//   - partA CHUNK 4096->2048: 782 blocks kills 135-block tail wave; LDS
//     37->21KB raises blocks/CU for sort-phase latency hiding.
//   - bn_stats f16x8 loads (was dword): 4x fewer load instructions.
// SpMM fp8: dual-edge half-wave dword gathers (R1 proven). spmm40: 6
// row-teams of 40 lanes (R1 proven). CSR entries 4B (u16 col | fp16 w).
// b0/b1 dropped (cancel in BN).
// ---------------------------------------------------------------------------

constexpr int   N_NODES   = 50000;
constexpr int   E_EDGES   = 1600000;
constexpr float BN_EPS    = 1e-5f;
constexpr int   K_BUCKETS = (N_NODES + 255) / 256;   // 196
constexpr int   BCAP      = 10240;
constexpr int   CHUNK     = 2048;
constexpr int   PART_BLK  = (E_EDGES + CHUNK - 1) / CHUNK;  // 782
constexpr int   PREP_BLK  = 152;                     // 38912 transpose items / 256
constexpr int   CG_SHIFT  = 12;
constexpr int   CG_N      = 16;
constexpr int   AITER     = CHUNK / 256;             // 8 edges/thread
constexpr int   TEAMS40   = 6;                       // row-teams per spmm40 block

typedef _Float16 f16x8 __attribute__((ext_vector_type(8)));
typedef float    f32x4 __attribute__((ext_vector_type(4)));
typedef float    f32x2 __attribute__((ext_vector_type(2)));

__device__ __forceinline__ float dec_w(unsigned u) {
  return __half2float(__ushort_as_half((unsigned short)(u >> 16)));
}

// ========================= W-transpose work item (prep) =========================
__device__ __forceinline__ void prep_item(int b, int k,
                                          const float* __restrict__ W0,
                                          const float* __restrict__ W1,
                                          const float* __restrict__ W2,
                                          __half* __restrict__ wt0,
                                          __half* __restrict__ wt1,
                                          __half* __restrict__ wt2) {
  if (b < 128) {
    wt0[b * 128 + k] = __float2half_rn(W0[k * 128 + b]);
  } else if (b < 256) {
    const int n = b - 128;
    wt1[n * 128 + k] = __float2half_rn(W1[k * 128 + n]);
  } else {
    const int n = b - 256;
    const float v = (n < 40) ? W2[k * 40 + n] : 0.f;
    wt2[n * 128 + k] = __float2half_rn(v);
  }
}

// ========================= partition phase A (+prep blocks) =========================
__global__ __launch_bounds__(256) void partA_prep_ker(const int* __restrict__ rows,
                                                      const int* __restrict__ cols,
                                                      const float* __restrict__ ew,
                                                      int* __restrict__ gcursor,
                                                      int2* __restrict__ ebuf,
                                                      const float* __restrict__ W0,
                                                      const float* __restrict__ W1,
                                                      const float* __restrict__ W2,
                                                      __half* __restrict__ wt0,
                                                      __half* __restrict__ wt1,
                                                      __half* __restrict__ wt2) {
  __shared__ int  cnt[256], cnt2[256], sc[256], offs[256], gbase[256];
  __shared__ int2 buf[CHUNK];
  const int tid = threadIdx.x;

  if (blockIdx.x >= PART_BLK) {  // prep blocks: W transposes (no barriers)
    const int item = (blockIdx.x - PART_BLK) * 256 + tid;  // < 38912
    prep_item(item >> 7, item & 127, W0, W1, W2, wt0, wt1, wt2);
    return;
  }

  cnt[tid] = 0; cnt2[tid] = 0;
  __syncthreads();

  const int e0   = blockIdx.x * CHUNK;
  const int ecnt = min(CHUNK, E_EDGES - e0);
  const bool full = (ecnt == CHUNK);

  int2 held[AITER];
  if (full) {
    // vectorized fast path: thread tid owns edges [tid*AITER, tid*AITER+AITER)
    const int4*   r4 = (const int4*)(rows + e0) + tid * (AITER / 4);
    const int4*   c4 = (const int4*)(cols + e0) + tid * (AITER / 4);
    const float4* w4 = (const float4*)(ew + e0) + tid * (AITER / 4);
#pragma unroll
    for (int v = 0; v < AITER / 4; ++v) {
      const int4   r = r4[v];
      const int4   c = c4[v];
      const float4 w = w4[v];
      const int rr[4] = {r.x, r.y, r.z, r.w};
      const int cc[4] = {c.x, c.y, c.z, c.w};
      const float ww[4] = {w.x, w.y, w.z, w.w};
#pragma unroll
      for (int s = 0; s < 4; ++s) {
        held[v * 4 + s].x = cc[s] | ((int)__half_as_ushort(__float2half_rn(ww[s])) << 16);
        held[v * 4 + s].y = rr[s];
        atomicAdd(&cnt[rr[s] >> 8], 1);
      }
    }
  } else {
#pragma unroll
    for (int j = 0; j < AITER; ++j) {
      const int i = tid + j * 256;
      if (i < ecnt) {
        const int   r = rows[e0 + i];
        const int   c = cols[e0 + i];
        const float w = ew[e0 + i];
        held[j].x = c | ((int)__half_as_ushort(__float2half_rn(w)) << 16);
        held[j].y = r;
        atomicAdd(&cnt[r >> 8], 1);
      }
    }
  }
  __syncthreads();

  sc[tid] = cnt[tid];
  __syncthreads();
  for (int o = 1; o < 256; o <<= 1) {
    int u = (tid >= o) ? sc[tid - o] : 0;
    __syncthreads();
    sc[tid] += u;
    __syncthreads();
  }
  offs[tid] = sc[tid] - cnt[tid];
  if (tid < K_BUCKETS && cnt[tid] > 0)
    gbase[tid] = atomicAdd(&gcursor[tid], cnt[tid]);
  __syncthreads();

#pragma unroll
  for (int j = 0; j < AITER; ++j) {
    if (full || (tid + j * 256) < ecnt) {
      const int b = held[j].y >> 8;
      const int p = offs[b] + atomicAdd(&cnt2[b], 1);
      buf[p] = held[j];
    }
  }
  __syncthreads();

  for (int i = tid; i < ecnt; i += 256) {
    const int2 v   = buf[i];
    const int  b   = v.y >> 8;
    const int  idx = gbase[b] + (i - offs[b]);
    if (idx < BCAP) ebuf[(long)b * BCAP + idx] = v;
  }
}

// ========================= partition phase B body (scan inlined) =========================
// smem carve: cnt[256*CG_N] | cur[256*CG_N] | sh[256] | sbase[1]  (33796 B)
__device__ void partB_body(const int b, char* smem,
                           const int* __restrict__ gcursor,
                           const int2* __restrict__ ebuf,
                           unsigned* __restrict__ se,
                           int* __restrict__ rowptr) {
  int* cnt = (int*)smem;
  int* cur = cnt + 256 * CG_N;
  int* sh  = cur + 256 * CG_N;
  int* sbp = sh + 256;
  const int tid = threadIdx.x;

  const int gv = (tid < K_BUCKETS) ? gcursor[tid] : 0;
  sh[tid] = gv;
  __syncthreads();
  for (int o = 1; o < 256; o <<= 1) {
    int u = (tid >= o) ? sh[tid - o] : 0;
    __syncthreads();
    sh[tid] += u;
    __syncthreads();
  }
  if (tid == b) *sbp = sh[tid] - gv;
  if (b == 0 && tid == 0) rowptr[N_NODES] = E_EDGES;

#pragma unroll
  for (int j = 0; j < CG_N; ++j) {
    cnt[tid * CG_N + j] = 0;
    cur[tid * CG_N + j] = 0;
  }
  __syncthreads();
  const int base = *sbp;
  const int cntb = min(gcursor[b], BCAP);

  const int2* __restrict__ src = ebuf + (long)b * BCAP;
  for (int i = tid; i < cntb; i += 256) {
    const int2 v = src[i];
    const int key = (v.y & 255) * CG_N + ((v.x & 0xFFFF) >> CG_SHIFT);
    atomicAdd(&cnt[key], 1);
  }
  __syncthreads();

  int loc[CG_N];
  int s = 0;
#pragma unroll
  for (int j = 0; j < CG_N; ++j) { loc[j] = s; s += cnt[tid * CG_N + j]; }
  sh[tid] = s;
  __syncthreads();
  for (int o = 1; o < 256; o <<= 1) {
    int u = (tid >= o) ? sh[tid - o] : 0;
    __syncthreads();
    sh[tid] += u;
    __syncthreads();
  }
  const int tb = sh[tid] - s;
#pragma unroll
  for (int j = 0; j < CG_N; ++j) cnt[tid * CG_N + j] = tb + loc[j];
  const int grow = b * 256 + tid;
  if (grow < N_NODES) rowptr[grow] = base + tb;
  __syncthreads();

  for (int i = tid; i < cntb; i += 256) {
    const int2 v   = src[i];
    const int  key = (v.y & 255) * CG_N + ((v.x & 0xFFFF) >> CG_SHIFT);
    const int  p   = cnt[key] + atomicAdd(&cur[key], 1);
    se[base + p] = (unsigned)v.x;
  }
}

// ========================= MFMA GEMM body =========================
// Hout = act(X) @ W ; X fp32 (layer 0) or fp16. OUT_FP8: fp8 e4m3 output.
// smem carve: Xs[64*PITCH f16] | Ws[FOUT_PAD*PITCH f16] | ssc[128] | ssh[128]
template <int FOUT, int FOUT_PAD, bool FUSE, bool OUT_FP8, typename XT>
__device__ __forceinline__ void gemm_body(const int bid, char* smem,
                                          const XT* __restrict__ X,
                                          const __half* __restrict__ Wt,
                                          void* __restrict__ Hout,
                                          const float* __restrict__ stats,
                                          const float* __restrict__ g,
                                          const float* __restrict__ be) {
  constexpr int CT    = FOUT_PAD / 16;
  constexpr int PITCH = 136;

  _Float16* Xs  = (_Float16*)smem;
  _Float16* Ws  = Xs + 64 * PITCH;
  float*    ssc = (float*)(Ws + FOUT_PAD * PITCH);
  float*    ssh = ssc + 128;

  const int tid  = threadIdx.x;
  const int row0 = bid * 64;

  if constexpr (FUSE) {
    if (tid < 128) {
      const float mean = stats[tid] * (1.0f / N_NODES);
      const float var  = stats[128 + tid] * (1.0f / N_NODES) - mean * mean;
      const float sc   = g[tid] * rsqrtf(var + BN_EPS);
      ssc[tid] = sc;
      ssh[tid] = be[tid] - mean * sc;
    }
    __syncthreads();
  }

  for (int i = tid; i < FOUT_PAD * 16; i += 256) {
    const int r  = i >> 4;
    const int c8 = (i & 15) * 8;
    *(f16x8*)(Ws + r * PITCH + c8) = *(const f16x8*)(Wt + r * 128 + c8);
  }

  if constexpr (sizeof(XT) == 4) {  // fp32 input (layer 0)
    for (int i = tid; i < 64 * 32; i += 256) {
      const int r  = i >> 5;
      const int k4 = (i & 31) * 4;
      const int gr = min(row0 + r, N_NODES - 1);
      float4 v = *(const float4*)((const float*)X + (long)gr * 128 + k4);
      _Float16* d = Xs + r * PITCH + k4;
      d[0] = (_Float16)v.x; d[1] = (_Float16)v.y;
      d[2] = (_Float16)v.z; d[3] = (_Float16)v.w;
    }
  } else {  // fp16 agg input
    for (int i = tid; i < 64 * 16; i += 256) {
      const int r  = i >> 4;
      const int k8 = (i & 15) * 8;
      const int gr = min(row0 + r, N_NODES - 1);
      f16x8 v = *(const f16x8*)((const _Float16*)X + (long)gr * 128 + k8);
      if constexpr (FUSE) {
#pragma unroll
        for (int j = 0; j < 8; ++j)
          v[j] = (_Float16)fmaxf((float)v[j] * ssc[k8 + j] + ssh[k8 + j], 0.f);
      }
      *(f16x8*)(Xs + r * PITCH + k8) = v;
    }
  }
  __syncthreads();

  const int wave = tid >> 6;
  const int lane = tid & 63;
  const int m    = lane & 15;
  const int q    = lane >> 4;
  const int rw   = wave * 16;

  f16x8 af[4];
  {
    const _Float16* ab = Xs + (rw + m) * PITCH + q * 8;
#pragma unroll
    for (int ks = 0; ks < 4; ++ks) af[ks] = *(const f16x8*)(ab + ks * 32);
  }

  f32x4 acc[CT];
#pragma unroll
  for (int ct = 0; ct < CT; ++ct) acc[ct] = (f32x4){0.f, 0.f, 0.f, 0.f};

#pragma unroll
  for (int ct = 0; ct < CT; ++ct) {
    const _Float16* bb = Ws + (ct * 16 + m) * PITCH + q * 8;
#pragma unroll
    for (int ks = 0; ks < 4; ++ks) {
      const f16x8 bf = *(const f16x8*)(bb + ks * 32);
      acc[ct] = __builtin_amdgcn_mfma_f32_16x16x32_f16(af[ks], bf, acc[ct], 0, 0, 0);
    }
  }

  __syncthreads();
#pragma unroll
  for (int ct = 0; ct < CT; ++ct) {
#pragma unroll
    for (int reg = 0; reg < 4; ++reg) {
      Xs[(rw + q * 4 + reg) * PITCH + ct * 16 + m] = (_Float16)acc[ct][reg];
    }
  }
  __syncthreads();

  if constexpr (OUT_FP8) {
    constexpr int C16 = FOUT / 16;  // 8
    unsigned char* H8 = (unsigned char*)Hout;
    for (int i = tid; i < 64 * C16; i += 256) {
      const int r   = i / C16;
      const int c16 = (i % C16) * 16;
      const int gr  = row0 + r;
      if (gr < N_NODES) {
        const _Float16* src = Xs + r * PITCH + c16;
        int w[4];
#pragma unroll
        for (int j = 0; j < 4; ++j) {
          int p = __builtin_amdgcn_cvt_pk_fp8_f32((float)src[4 * j + 0],
                                                  (float)src[4 * j + 1], 0, false);
          p = __builtin_amdgcn_cvt_pk_fp8_f32((float)src[4 * j + 2],
                                              (float)src[4 * j + 3], p, true);
          w[j] = p;
        }
        *(int4*)(H8 + (long)gr * FOUT + c16) = make_int4(w[0], w[1], w[2], w[3]);
      }
    }
  } else {
    constexpr int C8 = FOUT / 8;
    __half* H16 = (__half*)Hout;
    for (int i = tid; i < 64 * C8; i += 256) {
      const int r  = i / C8;
      const int c8 = (i % C8) * 8;
      const int gr = row0 + r;
      if (gr < N_NODES)
        *(f16x8*)(H16 + (long)gr * FOUT + c8) = *(const f16x8*)(Xs + r * PITCH + c8);
    }
  }
}

// ========================= merged partB + gemm0 kernel =========================
// blocks [0, K_BUCKETS): partB (CSR fine sort).  blocks [K_BUCKETS, +782):
// layer-0 GEMM (independent of CSR build) -> fills partB's idle CUs.
constexpr int SMEM_MERGED = (64 + 128) * 136 * 2 + 1024;  // 53248 B (> partB 33.8KB)

__global__ __launch_bounds__(256) void partB_gemm0_ker(const int* __restrict__ gcursor,
                                                       const int2* __restrict__ ebuf,
                                                       unsigned* __restrict__ se,
                                                       int* __restrict__ rowptr,
                                                       const float* __restrict__ x,
                                                       const __half* __restrict__ wt0,
                                                       unsigned char* __restrict__ h) {
  __shared__ __align__(16) char smem[SMEM_MERGED];
  if (blockIdx.x < K_BUCKETS) {
    partB_body(blockIdx.x, smem, gcursor, ebuf, se, rowptr);
  } else {
    gemm_body<128, 128, false, true, float>(blockIdx.x - K_BUCKETS, smem,
                                            x, wt0, h, nullptr, nullptr, nullptr);
  }
}

// ========================= standalone GEMM kernel (layers 1/2) =========================
template <int FOUT, int FOUT_PAD, bool FUSE, bool OUT_FP8, typename XT>
__global__ __launch_bounds__(256) void gemm_mfma_ker(const XT* __restrict__ X,
                                                     const __half* __restrict__ Wt,
                                                     void* __restrict__ Hout,
                                                     const float* __restrict__ stats,
                                                     const float* __restrict__ g,
                                                     const float* __restrict__ be) {
  __shared__ __align__(16) char smem[(64 + FOUT_PAD) * 136 * 2 + 1024];
  gemm_body<FOUT, FOUT_PAD, FUSE, OUT_FP8, XT>(blockIdx.x, smem, X, Wt, Hout, stats, g, be);
}

// ========================= CSR SpMM (fp8 H, 1 row/wave, dual-edge) =========================
// Half-wave split: lanes 0-31 process edge e, lanes 32-63 edge e+1; each lane
// loads a dword (4 fp8 cols), so one gather instruction covers 2 edges (256B).
// Unroll-16 keeps 16 edges in flight. __shfl_xor(32) merges the halves.
__global__ __launch_bounds__(256) void spmm_fp8_ker(const int* __restrict__ rowptr,
                                                    const unsigned* __restrict__ se,
                                                    const unsigned char* __restrict__ H,
                                                    __half* __restrict__ A) {
  const int gid  = blockIdx.x * 256 + threadIdx.x;
  const int lane = threadIdx.x & 63;
  const int hsel = lane >> 5;           // 0: lanes 0-31, 1: lanes 32-63
  const int l32  = lane & 31;
  const int wid  = __builtin_amdgcn_readfirstlane(gid >> 6);
  if (wid >= N_NODES) return;
  const int beg = rowptr[wid];
  const int end = rowptr[wid + 1];
  const unsigned* __restrict__ Hl = (const unsigned*)H + l32;  // row stride 32 dwords
  float a0 = 0.f, a1 = 0.f, a2 = 0.f, a3 = 0.f;

#define PAIR(U0, U1)                                                            \
  {                                                                             \
    const unsigned u_  = hsel ? (U1) : (U0);                                    \
    const unsigned d_  = Hl[(u_ & 0xFFFF) * 32];                                \
    const float    w_  = dec_w(u_);                                             \
    const f32x2    lo_ = __builtin_amdgcn_cvt_pk_f32_fp8((int)d_, false);       \
    const f32x2    hi_ = __builtin_amdgcn_cvt_pk_f32_fp8((int)d_, true);        \
    a0 += w_ * lo_[0]; a1 += w_ * lo_[1];                                       \
    a2 += w_ * hi_[0]; a3 += w_ * hi_[1];                                       \
  }

  int e = beg;
  {
    const int head = min(end - e, (4 - (e & 3)) & 3);
    for (int i = 0; i < head; i += 2) {
      const unsigned u0 = se[e + i];
      const unsigned u1 = (i + 1 < head) ? se[e + i + 1] : 0u;  // w=0 -> no-op
      PAIR(u0, u1)
    }
    e += head;
  }
  for (; e + 16 <= end; e += 16) {
    const uint4 a = *(const uint4*)(se + e);
    const uint4 b = *(const uint4*)(se + e + 4);
    const uint4 c = *(const uint4*)(se + e + 8);
    const uint4 d = *(const uint4*)(se + e + 12);
    PAIR(a.x, a.y) PAIR(a.z, a.w) PAIR(b.x, b.y) PAIR(b.z, b.w)
    PAIR(c.x, c.y) PAIR(c.z, c.w) PAIR(d.x, d.y) PAIR(d.z, d.w)
  }
  for (; e + 4 <= end; e += 4) {
    const uint4 a = *(const uint4*)(se + e);
    PAIR(a.x, a.y) PAIR(a.z, a.w)
  }
  for (; e < end; e += 2) {
    const unsigned u0 = se[e];
    const unsigned u1 = (e + 1 < end) ? se[e + 1] : 0u;
    PAIR(u0, u1)
  }
#undef PAIR

  a0 += __shfl_xor(a0, 32, 64);
  a1 += __shfl_xor(a1, 32, 64);
  a2 += __shfl_xor(a2, 32, 64);
  a3 += __shfl_xor(a3, 32, 64);

  if (lane < 32) {
    const __half2 h01 = __floats2half2_rn(a0, a1);
    const __half2 h23 = __floats2half2_rn(a2, a3);
    uint2 st;
    st.x = *(const unsigned*)&h01;
    st.y = *(const unsigned*)&h23;
    *(uint2*)((__half*)A + (long)wid * 128 + l32 * 4) = st;
  }
}

// ========================= CSR SpMM F=40 (fp16 H) + bias =========================
// 6 row-teams of 40 lanes per 256-thread block (240/256 active): lane util
// 94% vs 62.5% for one-row-per-wave. se loads are <=2-address broadcasts/wave.
__global__ __launch_bounds__(256) void spmm_csr40_ker(const int* __restrict__ rowptr,
                                                      const unsigned* __restrict__ se,
                                                      const __half* __restrict__ H,
                                                      const float* __restrict__ b,
                                                      float* __restrict__ out) {
  const int t    = threadIdx.x;
  const int team = t / 40;
  const int l    = t % 40;
  if (team >= TEAMS40) return;
  const int wid = blockIdx.x * TEAMS40 + team;
  if (wid >= N_NODES) return;
  const int beg = rowptr[wid];
  const int end = rowptr[wid + 1];
  float acc = 0.f;

#define F40_EDGE(U)                                                            \
  {                                                                            \
    const unsigned u_ = (U);                                                   \
    acc += dec_w(u_) * __half2float(H[(long)(u_ & 0xFFFF) * 40 + l]);          \
  }

  int e = beg;
  for (; e < end && (e & 3); ++e) F40_EDGE(se[e]);
  for (; e + 8 <= end; e += 8) {
    const uint4 a = *(const uint4*)(se + e);
    const uint4 c = *(const uint4*)(se + e + 4);
    F40_EDGE(a.x) F40_EDGE(a.y) F40_EDGE(a.z) F40_EDGE(a.w)
    F40_EDGE(c.x) F40_EDGE(c.y) F40_EDGE(c.z) F40_EDGE(c.w)
  }
  for (; e + 4 <= end; e += 4) {
    const uint4 a = *(const uint4*)(se + e);
    F40_EDGE(a.x) F40_EDGE(a.y) F40_EDGE(a.z) F40_EDGE(a.w)
  }
  for (; e < end; ++e) F40_EDGE(se[e]);
#undef F40_EDGE

  __builtin_nontemporal_store(acc + b[l], out + (long)wid * 40 + l);
}

// ========================= BatchNorm stats (fp16 input, f16x8 loads) =========================
// Thread owns 8 cols (c8), 16-row stride: 6-7 f16x8 loads per block-row-span.
// Private partials -> 16 LDS atomics/thread once -> 128 global atomics/block.
constexpr int BN_BLOCKS   = 512;
constexpr int BN_ROWS_PER = (N_NODES + BN_BLOCKS - 1) / BN_BLOCKS;  // 98

__global__ __launch_bounds__(256) void bn_stats_ker(const __half* __restrict__ A,
                                                    float* __restrict__ stats) {
  __shared__ float s_sh[128], q_sh[128];
  const int tid = threadIdx.x;
  if (tid < 128) { s_sh[tid] = 0.f; q_sh[tid] = 0.f; }
  __syncthreads();

  const int c8 = (tid & 15) * 8;
  const int rs = tid >> 4;  // 0..15
  const int r0 = blockIdx.x * BN_ROWS_PER;
  const int re = min(r0 + BN_ROWS_PER, N_NODES);
  float s[8] = {0.f, 0.f, 0.f, 0.f, 0.f, 0.f, 0.f, 0.f};
  float q[8] = {0.f, 0.f, 0.f, 0.f, 0.f, 0.f, 0.f, 0.f};
  for (int r = r0 + rs; r < re; r += 16) {
    const f16x8 v = *(const f16x8*)((const _Float16*)A + (long)r * 128 + c8);
#pragma unroll
    for (int j = 0; j < 8; ++j) {
      const float f = (float)v[j];
      s[j] += f; q[j] += f * f;
    }
  }
#pragma unroll
  for (int j = 0; j < 8; ++j) {
    atomicAdd(&s_sh[c8 + j], s[j]);
    atomicAdd(&q_sh[c8 + j], q[j]);
  }
  __syncthreads();
  if (tid < 128) {
    atomicAdd(&stats[tid],       s_sh[tid]);
    atomicAdd(&stats[128 + tid], q_sh[tid]);
  }
}

// ---------------------------------------------------------------------------
extern "C" void kernel_launch(void* const* d_in, const int* in_sizes, int n_in,
                              void* d_out, int out_size, void* d_ws, size_t ws_size,
                              hipStream_t stream) {
  const float* x    = (const float*)d_in[0];
  const int*   erow = (const int*)d_in[1];
  const int*   ecol = (const int*)d_in[2];
  const float* ew   = (const float*)d_in[3];
  const float* W0   = (const float*)d_in[4];
  const float* g0   = (const float*)d_in[6];
  const float* be0  = (const float*)d_in[7];
  const float* W1   = (const float*)d_in[8];
  const float* g1   = (const float*)d_in[10];
  const float* be1  = (const float*)d_in[11];
  const float* W2   = (const float*)d_in[12];
  const float* b2   = (const float*)d_in[13];
  float* out = (float*)d_out;

  // workspace layout (16B-aligned sections)
  unsigned char* h  = (unsigned char*)d_ws;                  // N*128 fp8 / N*40 fp16
  __half*   agg     = (__half*)(h + (long)N_NODES * 256);    // N*128 fp16
  float*    stats0  = (float*)(agg + (long)N_NODES * 128);   // 256
  float*    stats1  = stats0 + 256;                          // 256
  int*      gcursor = (int*)(stats1 + 256);                  // 256
  int*      rowptr  = gcursor + 256;                         // N+1 (pad 50004)
  unsigned* se      = (unsigned*)(rowptr + 50004);           // E (16B-aligned)
  int2*     ebuf    = (int2*)(se + E_EDGES);                 // K*BCAP
  __half*   wt0     = (__half*)(ebuf + (long)K_BUCKETS * BCAP);  // 128*128
  __half*   wt1     = wt0 + 128 * 128;                       // 128*128
  __half*   wt2     = wt1 + 128 * 128;                       // 48*128

  const int g_gemm   = (N_NODES + 63) / 64;                // 782
  const int g_spmm   = (N_NODES * 64) / 256;               // 12500
  const int g_spmm40 = (N_NODES + TEAMS40 - 1) / TEAMS40;  // 8334

  // ---- zero stats0 | stats1 | gcursor (contiguous 768 floats) ----
  hipMemsetAsync(stats0, 0, 768 * sizeof(float), stream);

  // ---- CSR phase A + W transposes (independent work, one launch) ----
  partA_prep_ker<<<PART_BLK + PREP_BLK, 256, 0, stream>>>(
      erow, ecol, ew, gcursor, ebuf, W0, W1, W2, wt0, wt1, wt2);

  // ---- CSR phase B (196 blocks) co-scheduled with layer-0 GEMM (782) ----
  partB_gemm0_ker<<<K_BUCKETS + g_gemm, 256, 0, stream>>>(
      gcursor, ebuf, se, rowptr, x, wt0, h);

  // ---- layer 0 aggregate (H fp8) ----
  spmm_fp8_ker<<<g_spmm, 256, 0, stream>>>(rowptr, se, h, agg);
  bn_stats_ker<<<BN_BLOCKS, 256, 0, stream>>>(agg, stats0);

  // ---- layer 1 (BN0 fused into GEMM staging; H fp8) ----
  gemm_mfma_ker<128, 128, true, true, _Float16><<<g_gemm, 256, 0, stream>>>(
      (const _Float16*)agg, wt1, h, stats0, g0, be0);
  spmm_fp8_ker<<<g_spmm, 256, 0, stream>>>(rowptr, se, h, agg);
  bn_stats_ker<<<BN_BLOCKS, 256, 0, stream>>>(agg, stats1);

  // ---- layer 2 (BN1 fused into GEMM; H fp16; bias b2 fused into SpMM) ----
  gemm_mfma_ker<40, 48, true, false, _Float16><<<g_gemm, 256, 0, stream>>>(
      (const _Float16*)agg, wt2, h, stats1, g1, be1);
  spmm_csr40_ker<<<g_spmm40, 256, 0, stream>>>(rowptr, se, (const __half*)h, b2, out);
}

// Round 10
// 303.334 us; speedup vs baseline: 1.0065x; 1.0065x over previous
//
#include <hip/hip_runtime.h>
#include <hip/hip_fp16.h>

// ---------------------------------------------------------------------------
// GCN: per-call CSR build (LDS-binned two-phase partition, scan inlined),
// then 3x (MFMA-f16 GEMM -> CSR-SpMM). H fp8 e4m3 for layers 0/1, fp16 for
// layer 2. BN stats separate; BN finalize+affine+ReLU fused into next GEMM.
// R7 (proven, 294.9us): prep merged into partA; partB merged with gemm0
// (block-range split + smem overlay); stats zero via hipMemsetAsync.
// R10 = R9 retry: NON-TEMPORAL hints in SpMM kernels via ext_vector_type
// (HIP uint4/uint2 are structs - rejected by the builtin). se edge stream
// (6.4MB/pass, zero reuse) + output stream no longer evict the H gather
// table (the reuse-bearing ~32x-reuse working set) from per-XCD L2.
// R8 lesson: partA CHUNK=4096 / CG_N=8 are a local optimum. R4/R6: no
// row-splitting, no wider-than-dual gathers.
// SpMM fp8: dual-edge half-wave dword gathers. spmm40: 6 row-teams of 40.
// CSR entries 4B (u16 col | fp16 w). b0/b1 dropped (cancel in BN).
// ---------------------------------------------------------------------------

constexpr int   N_NODES   = 50000;
constexpr int   E_EDGES   = 1600000;
constexpr float BN_EPS    = 1e-5f;
constexpr int   K_BUCKETS = (N_NODES + 255) / 256;   // 196
constexpr int   BCAP      = 10240;
constexpr int   CHUNK     = 4096;
constexpr int   PART_BLK  = (E_EDGES + CHUNK - 1) / CHUNK;  // 391
constexpr int   PREP_BLK  = 152;                     // 38912 transpose items / 256
constexpr int   CG_SHIFT  = 13;
constexpr int   CG_N      = 8;
constexpr int   AITER     = CHUNK / 256;             // 16 edges/thread
constexpr int   TEAMS40   = 6;                       // row-teams per spmm40 block

typedef _Float16 f16x8 __attribute__((ext_vector_type(8)));
typedef float    f32x4 __attribute__((ext_vector_type(4)));
typedef float    f32x2 __attribute__((ext_vector_type(2)));
typedef unsigned u32x4 __attribute__((ext_vector_type(4)));
typedef unsigned u32x2 __attribute__((ext_vector_type(2)));

__device__ __forceinline__ float dec_w(unsigned u) {
  return __half2float(__ushort_as_half((unsigned short)(u >> 16)));
}

// ========================= W-transpose work item (prep) =========================
__device__ __forceinline__ void prep_item(int b, int k,
                                          const float* __restrict__ W0,
                                          const float* __restrict__ W1,
                                          const float* __restrict__ W2,
                                          __half* __restrict__ wt0,
                                          __half* __restrict__ wt1,
                                          __half* __restrict__ wt2) {
  if (b < 128) {
    wt0[b * 128 + k] = __float2half_rn(W0[k * 128 + b]);
  } else if (b < 256) {
    const int n = b - 128;
    wt1[n * 128 + k] = __float2half_rn(W1[k * 128 + n]);
  } else {
    const int n = b - 256;
    const float v = (n < 40) ? W2[k * 40 + n] : 0.f;
    wt2[n * 128 + k] = __float2half_rn(v);
  }
}

// ========================= partition phase A (+prep blocks) =========================
__global__ __launch_bounds__(256) void partA_prep_ker(const int* __restrict__ rows,
                                                      const int* __restrict__ cols,
                                                      const float* __restrict__ ew,
                                                      int* __restrict__ gcursor,
                                                      int2* __restrict__ ebuf,
                                                      const float* __restrict__ W0,
                                                      const float* __restrict__ W1,
                                                      const float* __restrict__ W2,
                                                      __half* __restrict__ wt0,
                                                      __half* __restrict__ wt1,
                                                      __half* __restrict__ wt2) {
  __shared__ int  cnt[256], cnt2[256], sc[256], offs[256], gbase[256];
  __shared__ int2 buf[CHUNK];
  const int tid = threadIdx.x;

  if (blockIdx.x >= PART_BLK) {  // prep blocks: W transposes (no barriers)
    const int item = (blockIdx.x - PART_BLK) * 256 + tid;  // < 38912
    prep_item(item >> 7, item & 127, W0, W1, W2, wt0, wt1, wt2);
    return;
  }

  cnt[tid] = 0; cnt2[tid] = 0;
  __syncthreads();

  const int e0   = blockIdx.x * CHUNK;
  const int ecnt = min(CHUNK, E_EDGES - e0);
  const bool full = (ecnt == CHUNK);

  int2 held[AITER];
  if (full) {
    // vectorized fast path: thread tid owns edges [tid*16, tid*16+16)
    const int4*   r4 = (const int4*)(rows + e0) + tid * (AITER / 4);
    const int4*   c4 = (const int4*)(cols + e0) + tid * (AITER / 4);
    const float4* w4 = (const float4*)(ew + e0) + tid * (AITER / 4);
#pragma unroll
    for (int v = 0; v < AITER / 4; ++v) {
      const int4   r = r4[v];
      const int4   c = c4[v];
      const float4 w = w4[v];
      const int rr[4] = {r.x, r.y, r.z, r.w};
      const int cc[4] = {c.x, c.y, c.z, c.w};
      const float ww[4] = {w.x, w.y, w.z, w.w};
#pragma unroll
      for (int s = 0; s < 4; ++s) {
        held[v * 4 + s].x = cc[s] | ((int)__half_as_ushort(__float2half_rn(ww[s])) << 16);
        held[v * 4 + s].y = rr[s];
        atomicAdd(&cnt[rr[s] >> 8], 1);
      }
    }
  } else {
#pragma unroll
    for (int j = 0; j < AITER; ++j) {
      const int i = tid + j * 256;
      if (i < ecnt) {
        const int   r = rows[e0 + i];
        const int   c = cols[e0 + i];
        const float w = ew[e0 + i];
        held[j].x = c | ((int)__half_as_ushort(__float2half_rn(w)) << 16);
        held[j].y = r;
        atomicAdd(&cnt[r >> 8], 1);
      }
    }
  }
  __syncthreads();

  sc[tid] = cnt[tid];
  __syncthreads();
  for (int o = 1; o < 256; o <<= 1) {
    int u = (tid >= o) ? sc[tid - o] : 0;
    __syncthreads();
    sc[tid] += u;
    __syncthreads();
  }
  offs[tid] = sc[tid] - cnt[tid];
  if (tid < K_BUCKETS && cnt[tid] > 0)
    gbase[tid] = atomicAdd(&gcursor[tid], cnt[tid]);
  __syncthreads();

#pragma unroll
  for (int j = 0; j < AITER; ++j) {
    if (full || (tid + j * 256) < ecnt) {
      const int b = held[j].y >> 8;
      const int p = offs[b] + atomicAdd(&cnt2[b], 1);
      buf[p] = held[j];
    }
  }
  __syncthreads();

  for (int i = tid; i < ecnt; i += 256) {
    const int2 v   = buf[i];
    const int  b   = v.y >> 8;
    const int  idx = gbase[b] + (i - offs[b]);
    if (idx < BCAP) ebuf[(long)b * BCAP + idx] = v;
  }
}

// ========================= partition phase B body (scan inlined) =========================
// smem carve: cnt[2048] | cur[2048] | sh[256] | sbase[1]  (17412 B)
__device__ void partB_body(const int b, char* smem,
                           const int* __restrict__ gcursor,
                           const int2* __restrict__ ebuf,
                           unsigned* __restrict__ se,
                           int* __restrict__ rowptr) {
  int* cnt = (int*)smem;
  int* cur = cnt + 256 * CG_N;
  int* sh  = cur + 256 * CG_N;
  int* sbp = sh + 256;
  const int tid = threadIdx.x;

  const int gv = (tid < K_BUCKETS) ? gcursor[tid] : 0;
  sh[tid] = gv;
  __syncthreads();
  for (int o = 1; o < 256; o <<= 1) {
    int u = (tid >= o) ? sh[tid - o] : 0;
    __syncthreads();
    sh[tid] += u;
    __syncthreads();
  }
  if (tid == b) *sbp = sh[tid] - gv;
  if (b == 0 && tid == 0) rowptr[N_NODES] = E_EDGES;

#pragma unroll
  for (int j = 0; j < CG_N; ++j) {
    cnt[tid * CG_N + j] = 0;
    cur[tid * CG_N + j] = 0;
  }
  __syncthreads();
  const int base = *sbp;
  const int cntb = min(gcursor[b], BCAP);

  const int2* __restrict__ src = ebuf + (long)b * BCAP;
  for (int i = tid; i < cntb; i += 256) {
    const int2 v = src[i];
    const int key = (v.y & 255) * CG_N + ((v.x & 0xFFFF) >> CG_SHIFT);
    atomicAdd(&cnt[key], 1);
  }
  __syncthreads();

  int loc[CG_N];
  int s = 0;
#pragma unroll
  for (int j = 0; j < CG_N; ++j) { loc[j] = s; s += cnt[tid * CG_N + j]; }
  sh[tid] = s;
  __syncthreads();
  for (int o = 1; o < 256; o <<= 1) {
    int u = (tid >= o) ? sh[tid - o] : 0;
    __syncthreads();
    sh[tid] += u;
    __syncthreads();
  }
  const int tb = sh[tid] - s;
#pragma unroll
  for (int j = 0; j < CG_N; ++j) cnt[tid * CG_N + j] = tb + loc[j];
  const int grow = b * 256 + tid;
  if (grow < N_NODES) rowptr[grow] = base + tb;
  __syncthreads();

  for (int i = tid; i < cntb; i += 256) {
    const int2 v   = src[i];
    const int  key = (v.y & 255) * CG_N + ((v.x & 0xFFFF) >> CG_SHIFT);
    const int  p   = cnt[key] + atomicAdd(&cur[key], 1);
    se[base + p] = (unsigned)v.x;
  }
}

// ========================= MFMA GEMM body =========================
// Hout = act(X) @ W ; X fp32 (layer 0) or fp16. OUT_FP8: fp8 e4m3 output.
// smem carve: Xs[64*PITCH f16] | Ws[FOUT_PAD*PITCH f16] | ssc[128] | ssh[128]
template <int FOUT, int FOUT_PAD, bool FUSE, bool OUT_FP8, typename XT>
__device__ __forceinline__ void gemm_body(const int bid, char* smem,
                                          const XT* __restrict__ X,
                                          const __half* __restrict__ Wt,
                                          void* __restrict__ Hout,
                                          const float* __restrict__ stats,
                                          const float* __restrict__ g,
                                          const float* __restrict__ be) {
  constexpr int CT    = FOUT_PAD / 16;
  constexpr int PITCH = 136;

  _Float16* Xs  = (_Float16*)smem;
  _Float16* Ws  = Xs + 64 * PITCH;
  float*    ssc = (float*)(Ws + FOUT_PAD * PITCH);
  float*    ssh = ssc + 128;

  const int tid  = threadIdx.x;
  const int row0 = bid * 64;

  if constexpr (FUSE) {
    if (tid < 128) {
      const float mean = stats[tid] * (1.0f / N_NODES);
      const float var  = stats[128 + tid] * (1.0f / N_NODES) - mean * mean;
      const float sc   = g[tid] * rsqrtf(var + BN_EPS);
      ssc[tid] = sc;
      ssh[tid] = be[tid] - mean * sc;
    }
    __syncthreads();
  }

  for (int i = tid; i < FOUT_PAD * 16; i += 256) {
    const int r  = i >> 4;
    const int c8 = (i & 15) * 8;
    *(f16x8*)(Ws + r * PITCH + c8) = *(const f16x8*)(Wt + r * 128 + c8);
  }

  if constexpr (sizeof(XT) == 4) {  // fp32 input (layer 0)
    for (int i = tid; i < 64 * 32; i += 256) {
      const int r  = i >> 5;
      const int k4 = (i & 31) * 4;
      const int gr = min(row0 + r, N_NODES - 1);
      float4 v = *(const float4*)((const float*)X + (long)gr * 128 + k4);
      _Float16* d = Xs + r * PITCH + k4;
      d[0] = (_Float16)v.x; d[1] = (_Float16)v.y;
      d[2] = (_Float16)v.z; d[3] = (_Float16)v.w;
    }
  } else {  // fp16 agg input
    for (int i = tid; i < 64 * 16; i += 256) {
      const int r  = i >> 4;
      const int k8 = (i & 15) * 8;
      const int gr = min(row0 + r, N_NODES - 1);
      f16x8 v = *(const f16x8*)((const _Float16*)X + (long)gr * 128 + k8);
      if constexpr (FUSE) {
#pragma unroll
        for (int j = 0; j < 8; ++j)
          v[j] = (_Float16)fmaxf((float)v[j] * ssc[k8 + j] + ssh[k8 + j], 0.f);
      }
      *(f16x8*)(Xs + r * PITCH + k8) = v;
    }
  }
  __syncthreads();

  const int wave = tid >> 6;
  const int lane = tid & 63;
  const int m    = lane & 15;
  const int q    = lane >> 4;
  const int rw   = wave * 16;

  f16x8 af[4];
  {
    const _Float16* ab = Xs + (rw + m) * PITCH + q * 8;
#pragma unroll
    for (int ks = 0; ks < 4; ++ks) af[ks] = *(const f16x8*)(ab + ks * 32);
  }

  f32x4 acc[CT];
#pragma unroll
  for (int ct = 0; ct < CT; ++ct) acc[ct] = (f32x4){0.f, 0.f, 0.f, 0.f};

#pragma unroll
  for (int ct = 0; ct < CT; ++ct) {
    const _Float16* bb = Ws + (ct * 16 + m) * PITCH + q * 8;
#pragma unroll
    for (int ks = 0; ks < 4; ++ks) {
      const f16x8 bf = *(const f16x8*)(bb + ks * 32);
      acc[ct] = __builtin_amdgcn_mfma_f32_16x16x32_f16(af[ks], bf, acc[ct], 0, 0, 0);
    }
  }

  __syncthreads();
#pragma unroll
  for (int ct = 0; ct < CT; ++ct) {
#pragma unroll
    for (int reg = 0; reg < 4; ++reg) {
      Xs[(rw + q * 4 + reg) * PITCH + ct * 16 + m] = (_Float16)acc[ct][reg];
    }
  }
  __syncthreads();

  if constexpr (OUT_FP8) {
    constexpr int C16 = FOUT / 16;  // 8
    unsigned char* H8 = (unsigned char*)Hout;
    for (int i = tid; i < 64 * C16; i += 256) {
      const int r   = i / C16;
      const int c16 = (i % C16) * 16;
      const int gr  = row0 + r;
      if (gr < N_NODES) {
        const _Float16* src = Xs + r * PITCH + c16;
        int w[4];
#pragma unroll
        for (int j = 0; j < 4; ++j) {
          int p = __builtin_amdgcn_cvt_pk_fp8_f32((float)src[4 * j + 0],
                                                  (float)src[4 * j + 1], 0, false);
          p = __builtin_amdgcn_cvt_pk_fp8_f32((float)src[4 * j + 2],
                                              (float)src[4 * j + 3], p, true);
          w[j] = p;
        }
        *(int4*)(H8 + (long)gr * FOUT + c16) = make_int4(w[0], w[1], w[2], w[3]);
      }
    }
  } else {
    constexpr int C8 = FOUT / 8;
    __half* H16 = (__half*)Hout;
    for (int i = tid; i < 64 * C8; i += 256) {
      const int r  = i / C8;
      const int c8 = (i % C8) * 8;
      const int gr = row0 + r;
      if (gr < N_NODES)
        *(f16x8*)(H16 + (long)gr * FOUT + c8) = *(const f16x8*)(Xs + r * PITCH + c8);
    }
  }
}

// ========================= merged partB + gemm0 kernel =========================
// blocks [0, K_BUCKETS): partB (CSR fine sort).  blocks [K_BUCKETS, +782):
// layer-0 GEMM (independent of CSR build) -> fills partB's idle CUs.
constexpr int SMEM_MERGED = (64 + 128) * 136 * 2 + 1024;  // 53248 B (gemm > partB 17KB)

__global__ __launch_bounds__(256) void partB_gemm0_ker(const int* __restrict__ gcursor,
                                                       const int2* __restrict__ ebuf,
                                                       unsigned* __restrict__ se,
                                                       int* __restrict__ rowptr,
                                                       const float* __restrict__ x,
                                                       const __half* __restrict__ wt0,
                                                       unsigned char* __restrict__ h) {
  __shared__ __align__(16) char smem[SMEM_MERGED];
  if (blockIdx.x < K_BUCKETS) {
    partB_body(blockIdx.x, smem, gcursor, ebuf, se, rowptr);
  } else {
    gemm_body<128, 128, false, true, float>(blockIdx.x - K_BUCKETS, smem,
                                            x, wt0, h, nullptr, nullptr, nullptr);
  }
}

// ========================= standalone GEMM kernel (layers 1/2) =========================
template <int FOUT, int FOUT_PAD, bool FUSE, bool OUT_FP8, typename XT>
__global__ __launch_bounds__(256) void gemm_mfma_ker(const XT* __restrict__ X,
                                                     const __half* __restrict__ Wt,
                                                     void* __restrict__ Hout,
                                                     const float* __restrict__ stats,
                                                     const float* __restrict__ g,
                                                     const float* __restrict__ be) {
  __shared__ __align__(16) char smem[(64 + FOUT_PAD) * 136 * 2 + 1024];
  gemm_body<FOUT, FOUT_PAD, FUSE, OUT_FP8, XT>(blockIdx.x, smem, X, Wt, Hout, stats, g, be);
}

// ========================= CSR SpMM (fp8 H, 1 row/wave, dual-edge, nt-streams) ========
// Half-wave split: lanes 0-31 process edge e, lanes 32-63 edge e+1; each lane
// loads a dword (4 fp8 cols), so one gather instruction covers 2 edges (256B).
// Unroll-16 keeps 16 edges in flight. __shfl_xor(32) merges the halves.
// se (zero-reuse stream) read non-temporally; A stored non-temporally ->
// per-XCD L2 capacity reserved for the reuse-bearing H gather table.
__global__ __launch_bounds__(256) void spmm_fp8_ker(const int* __restrict__ rowptr,
                                                    const unsigned* __restrict__ se,
                                                    const unsigned char* __restrict__ H,
                                                    __half* __restrict__ A) {
  const int gid  = blockIdx.x * 256 + threadIdx.x;
  const int lane = threadIdx.x & 63;
  const int hsel = lane >> 5;           // 0: lanes 0-31, 1: lanes 32-63
  const int l32  = lane & 31;
  const int wid  = __builtin_amdgcn_readfirstlane(gid >> 6);
  if (wid >= N_NODES) return;
  const int beg = rowptr[wid];
  const int end = rowptr[wid + 1];
  const unsigned* __restrict__ Hl = (const unsigned*)H + l32;  // row stride 32 dwords
  float a0 = 0.f, a1 = 0.f, a2 = 0.f, a3 = 0.f;

#define PAIR(U0, U1)                                                            \
  {                                                                             \
    const unsigned u_  = hsel ? (U1) : (U0);                                    \
    const unsigned d_  = Hl[(u_ & 0xFFFF) * 32];                                \
    const float    w_  = dec_w(u_);                                             \
    const f32x2    lo_ = __builtin_amdgcn_cvt_pk_f32_fp8((int)d_, false);       \
    const f32x2    hi_ = __builtin_amdgcn_cvt_pk_f32_fp8((int)d_, true);        \
    a0 += w_ * lo_[0]; a1 += w_ * lo_[1];                                       \
    a2 += w_ * hi_[0]; a3 += w_ * hi_[1];                                       \
  }

  int e = beg;
  {
    const int head = min(end - e, (4 - (e & 3)) & 3);
    for (int i = 0; i < head; i += 2) {
      const unsigned u0 = se[e + i];
      const unsigned u1 = (i + 1 < head) ? se[e + i + 1] : 0u;  // w=0 -> no-op
      PAIR(u0, u1)
    }
    e += head;
  }
  for (; e + 16 <= end; e += 16) {
    const u32x4 a = __builtin_nontemporal_load((const u32x4*)(se + e));
    const u32x4 b = __builtin_nontemporal_load((const u32x4*)(se + e + 4));
    const u32x4 c = __builtin_nontemporal_load((const u32x4*)(se + e + 8));
    const u32x4 d = __builtin_nontemporal_load((const u32x4*)(se + e + 12));
    PAIR(a.x, a.y) PAIR(a.z, a.w) PAIR(b.x, b.y) PAIR(b.z, b.w)
    PAIR(c.x, c.y) PAIR(c.z, c.w) PAIR(d.x, d.y) PAIR(d.z, d.w)
  }
  for (; e + 4 <= end; e += 4) {
    const u32x4 a = __builtin_nontemporal_load((const u32x4*)(se + e));
    PAIR(a.x, a.y) PAIR(a.z, a.w)
  }
  for (; e < end; e += 2) {
    const unsigned u0 = se[e];
    const unsigned u1 = (e + 1 < end) ? se[e + 1] : 0u;
    PAIR(u0, u1)
  }
#undef PAIR

  a0 += __shfl_xor(a0, 32, 64);
  a1 += __shfl_xor(a1, 32, 64);
  a2 += __shfl_xor(a2, 32, 64);
  a3 += __shfl_xor(a3, 32, 64);

  if (lane < 32) {
    const __half2 h01 = __floats2half2_rn(a0, a1);
    const __half2 h23 = __floats2half2_rn(a2, a3);
    u32x2 st;
    st.x = *(const unsigned*)&h01;
    st.y = *(const unsigned*)&h23;
    __builtin_nontemporal_store(st, (u32x2*)((__half*)A + (long)wid * 128 + l32 * 4));
  }
}

// ========================= CSR SpMM F=40 (fp16 H) + bias, nt-streams =========================
// 6 row-teams of 40 lanes per 256-thread block (240/256 active): lane util
// 94% vs 62.5% for one-row-per-wave. se loads are <=2-address broadcasts/wave.
__global__ __launch_bounds__(256) void spmm_csr40_ker(const int* __restrict__ rowptr,
                                                      const unsigned* __restrict__ se,
                                                      const __half* __restrict__ H,
                                                      const float* __restrict__ b,
                                                      float* __restrict__ out) {
  const int t    = threadIdx.x;
  const int team = t / 40;
  const int l    = t % 40;
  if (team >= TEAMS40) return;
  const int wid = blockIdx.x * TEAMS40 + team;
  if (wid >= N_NODES) return;
  const int beg = rowptr[wid];
  const int end = rowptr[wid + 1];
  float acc = 0.f;

#define F40_EDGE(U)                                                            \
  {                                                                            \
    const unsigned u_ = (U);                                                   \
    acc += dec_w(u_) * __half2float(H[(long)(u_ & 0xFFFF) * 40 + l]);          \
  }

  int e = beg;
  for (; e < end && (e & 3); ++e) F40_EDGE(se[e]);
  for (; e + 8 <= end; e += 8) {
    const u32x4 a = __builtin_nontemporal_load((const u32x4*)(se + e));
    const u32x4 c = __builtin_nontemporal_load((const u32x4*)(se + e + 4));
    F40_EDGE(a.x) F40_EDGE(a.y) F40_EDGE(a.z) F40_EDGE(a.w)
    F40_EDGE(c.x) F40_EDGE(c.y) F40_EDGE(c.z) F40_EDGE(c.w)
  }
  for (; e + 4 <= end; e += 4) {
    const u32x4 a = __builtin_nontemporal_load((const u32x4*)(se + e));
    F40_EDGE(a.x) F40_EDGE(a.y) F40_EDGE(a.z) F40_EDGE(a.w)
  }
  for (; e < end; ++e) F40_EDGE(se[e]);
#undef F40_EDGE

  __builtin_nontemporal_store(acc + b[l], out + (long)wid * 40 + l);
}

// ========================= BatchNorm stats (fp16 input) =========================
// half2 loads (thread owns a col pair, 4-row stride), LDS block reduce,
// 128 global atomics per block (131K total, half of the per-thread scheme).
constexpr int BN_BLOCKS   = 512;
constexpr int BN_ROWS_PER = (N_NODES + BN_BLOCKS - 1) / BN_BLOCKS;  // 98

__global__ __launch_bounds__(256) void bn_stats_ker(const __half* __restrict__ A,
                                                    float* __restrict__ stats) {
  __shared__ float s_sh[128], q_sh[128];
  const int tid = threadIdx.x;
  if (tid < 128) { s_sh[tid] = 0.f; q_sh[tid] = 0.f; }
  __syncthreads();

  const int c2 = (tid & 63) * 2;
  const int rs = tid >> 6;  // 0..3
  const int r0 = blockIdx.x * BN_ROWS_PER;
  const int re = min(r0 + BN_ROWS_PER, N_NODES);
  float s0 = 0.f, s1 = 0.f, q0 = 0.f, q1 = 0.f;
  for (int r = r0 + rs; r < re; r += 4) {
    const float2 v = __half22float2(*(const __half2*)(A + (long)r * 128 + c2));
    s0 += v.x; q0 += v.x * v.x;
    s1 += v.y; q1 += v.y * v.y;
  }
  atomicAdd(&s_sh[c2 + 0], s0);
  atomicAdd(&s_sh[c2 + 1], s1);
  atomicAdd(&q_sh[c2 + 0], q0);
  atomicAdd(&q_sh[c2 + 1], q1);
  __syncthreads();
  if (tid < 128) {
    atomicAdd(&stats[tid],       s_sh[tid]);
    atomicAdd(&stats[128 + tid], q_sh[tid]);
  }
}

// ---------------------------------------------------------------------------
extern "C" void kernel_launch(void* const* d_in, const int* in_sizes, int n_in,
                              void* d_out, int out_size, void* d_ws, size_t ws_size,
                              hipStream_t stream) {
  const float* x    = (const float*)d_in[0];
  const int*   erow = (const int*)d_in[1];
  const int*   ecol = (const int*)d_in[2];
  const float* ew   = (const float*)d_in[3];
  const float* W0   = (const float*)d_in[4];
  const float* g0   = (const float*)d_in[6];
  const float* be0  = (const float*)d_in[7];
  const float* W1   = (const float*)d_in[8];
  const float* g1   = (const float*)d_in[10];
  const float* be1  = (const float*)d_in[11];
  const float* W2   = (const float*)d_in[12];
  const float* b2   = (const float*)d_in[13];
  float* out = (float*)d_out;

  // workspace layout (16B-aligned sections)
  unsigned char* h  = (unsigned char*)d_ws;                  // N*128 fp8 / N*40 fp16
  __half*   agg     = (__half*)(h + (long)N_NODES * 256);    // N*128 fp16
  float*    stats0  = (float*)(agg + (long)N_NODES * 128);   // 256
  float*    stats1  = stats0 + 256;                          // 256
  int*      gcursor = (int*)(stats1 + 256);                  // 256
  int*      rowptr  = gcursor + 256;                         // N+1 (pad 50004)
  unsigned* se      = (unsigned*)(rowptr + 50004);           // E (16B-aligned)
  int2*     ebuf    = (int2*)(se + E_EDGES);                 // K*BCAP
  __half*   wt0     = (__half*)(ebuf + (long)K_BUCKETS * BCAP);  // 128*128
  __half*   wt1     = wt0 + 128 * 128;                       // 128*128
  __half*   wt2     = wt1 + 128 * 128;                       // 48*128

  const int g_gemm   = (N_NODES + 63) / 64;                // 782
  const int g_spmm   = (N_NODES * 64) / 256;               // 12500
  const int g_spmm40 = (N_NODES + TEAMS40 - 1) / TEAMS40;  // 8334

  // ---- zero stats0 | stats1 | gcursor (contiguous 768 floats) ----
  (void)hipMemsetAsync(stats0, 0, 768 * sizeof(float), stream);

  // ---- CSR phase A + W transposes (independent work, one launch) ----
  partA_prep_ker<<<PART_BLK + PREP_BLK, 256, 0, stream>>>(
      erow, ecol, ew, gcursor, ebuf, W0, W1, W2, wt0, wt1, wt2);

  // ---- CSR phase B (196 blocks) co-scheduled with layer-0 GEMM (782) ----
  partB_gemm0_ker<<<K_BUCKETS + g_gemm, 256, 0, stream>>>(
      gcursor, ebuf, se, rowptr, x, wt0, h);

  // ---- layer 0 aggregate (H fp8) ----
  spmm_fp8_ker<<<g_spmm, 256, 0, stream>>>(rowptr, se, h, agg);
  bn_stats_ker<<<BN_BLOCKS, 256, 0, stream>>>(agg, stats0);

  // ---- layer 1 (BN0 fused into GEMM staging; H fp8) ----
  gemm_mfma_ker<128, 128, true, true, _Float16><<<g_gemm, 256, 0, stream>>>(
      (const _Float16*)agg, wt1, h, stats0, g0, be0);
  spmm_fp8_ker<<<g_spmm, 256, 0, stream>>>(rowptr, se, h, agg);
  bn_stats_ker<<<BN_BLOCKS, 256, 0, stream>>>(agg, stats1);

  // ---- layer 2 (BN1 fused into GEMM; H fp16; bias b2 fused into SpMM) ----
  gemm_mfma_ker<40, 48, true, false, _Float16><<<g_gemm, 256, 0, stream>>>(
      (const _Float16*)agg, wt2, h, stats1, g1, be1);
  spmm_csr40_ker<<<g_spmm40, 256, 0, stream>>>(rowptr, se, (const __half*)h, b2, out);
}

// Round 11
// 290.702 us; speedup vs baseline: 1.0503x; 1.0435x over previous
//
#include <hip/hip_runtime.h>
#include <hip/hip_fp16.h>

// ---------------------------------------------------------------------------
// GCN: per-call CSR build (LDS-binned two-phase partition, scan inlined),
// then 3x (MFMA-f16 GEMM -> CSR-SpMM). H fp8 e4m3 for layers 0/1, fp16 for
// layer 2. BN stats separate; BN finalize+affine+ReLU fused into next GEMM.
// R7 (proven, 294.9us): prep merged into partA; partB merged with gemm0
// (block-range split + smem overlay); stats zero via hipMemsetAsync.
// R11 single change: spmm40 -> 12 teams of 20 lanes, __half2 H loads (was
// 40 lanes x scalar 2B), float2 out stores; 4167 blocks (was 8334). Same
// 1-gather/edge structure, same per-column sum order (bitwise-identical).
// R10 lesson: NO non-temporal hints - intermediates (agg/out/se) have
// cross-kernel L2 reuse; nt stores forced consumers to HBM (+8us).
// R8 lesson: partA CHUNK=4096 / CG_N=8 are a local optimum. R4/R6: no
// row-splitting, no wider-than-dual fp8 gathers.
// SpMM fp8: dual-edge half-wave dword gathers. CSR entries 4B
// (u16 col | fp16 w). b0/b1 dropped (cancel in BN).
// ---------------------------------------------------------------------------

constexpr int   N_NODES   = 50000;
constexpr int   E_EDGES   = 1600000;
constexpr float BN_EPS    = 1e-5f;
constexpr int   K_BUCKETS = (N_NODES + 255) / 256;   // 196
constexpr int   BCAP      = 10240;
constexpr int   CHUNK     = 4096;
constexpr int   PART_BLK  = (E_EDGES + CHUNK - 1) / CHUNK;  // 391
constexpr int   PREP_BLK  = 152;                     // 38912 transpose items / 256
constexpr int   CG_SHIFT  = 13;
constexpr int   CG_N      = 8;
constexpr int   AITER     = CHUNK / 256;             // 16 edges/thread
constexpr int   TEAMS20   = 12;                      // 20-lane row-teams per block

typedef _Float16 f16x8 __attribute__((ext_vector_type(8)));
typedef float    f32x4 __attribute__((ext_vector_type(4)));
typedef float    f32x2 __attribute__((ext_vector_type(2)));

__device__ __forceinline__ float dec_w(unsigned u) {
  return __half2float(__ushort_as_half((unsigned short)(u >> 16)));
}

// ========================= W-transpose work item (prep) =========================
__device__ __forceinline__ void prep_item(int b, int k,
                                          const float* __restrict__ W0,
                                          const float* __restrict__ W1,
                                          const float* __restrict__ W2,
                                          __half* __restrict__ wt0,
                                          __half* __restrict__ wt1,
                                          __half* __restrict__ wt2) {
  if (b < 128) {
    wt0[b * 128 + k] = __float2half_rn(W0[k * 128 + b]);
  } else if (b < 256) {
    const int n = b - 128;
    wt1[n * 128 + k] = __float2half_rn(W1[k * 128 + n]);
  } else {
    const int n = b - 256;
    const float v = (n < 40) ? W2[k * 40 + n] : 0.f;
    wt2[n * 128 + k] = __float2half_rn(v);
  }
}

// ========================= partition phase A (+prep blocks) =========================
__global__ __launch_bounds__(256) void partA_prep_ker(const int* __restrict__ rows,
                                                      const int* __restrict__ cols,
                                                      const float* __restrict__ ew,
                                                      int* __restrict__ gcursor,
                                                      int2* __restrict__ ebuf,
                                                      const float* __restrict__ W0,
                                                      const float* __restrict__ W1,
                                                      const float* __restrict__ W2,
                                                      __half* __restrict__ wt0,
                                                      __half* __restrict__ wt1,
                                                      __half* __restrict__ wt2) {
  __shared__ int  cnt[256], cnt2[256], sc[256], offs[256], gbase[256];
  __shared__ int2 buf[CHUNK];
  const int tid = threadIdx.x;

  if (blockIdx.x >= PART_BLK) {  // prep blocks: W transposes (no barriers)
    const int item = (blockIdx.x - PART_BLK) * 256 + tid;  // < 38912
    prep_item(item >> 7, item & 127, W0, W1, W2, wt0, wt1, wt2);
    return;
  }

  cnt[tid] = 0; cnt2[tid] = 0;
  __syncthreads();

  const int e0   = blockIdx.x * CHUNK;
  const int ecnt = min(CHUNK, E_EDGES - e0);
  const bool full = (ecnt == CHUNK);

  int2 held[AITER];
  if (full) {
    // vectorized fast path: thread tid owns edges [tid*16, tid*16+16)
    const int4*   r4 = (const int4*)(rows + e0) + tid * (AITER / 4);
    const int4*   c4 = (const int4*)(cols + e0) + tid * (AITER / 4);
    const float4* w4 = (const float4*)(ew + e0) + tid * (AITER / 4);
#pragma unroll
    for (int v = 0; v < AITER / 4; ++v) {
      const int4   r = r4[v];
      const int4   c = c4[v];
      const float4 w = w4[v];
      const int rr[4] = {r.x, r.y, r.z, r.w};
      const int cc[4] = {c.x, c.y, c.z, c.w};
      const float ww[4] = {w.x, w.y, w.z, w.w};
#pragma unroll
      for (int s = 0; s < 4; ++s) {
        held[v * 4 + s].x = cc[s] | ((int)__half_as_ushort(__float2half_rn(ww[s])) << 16);
        held[v * 4 + s].y = rr[s];
        atomicAdd(&cnt[rr[s] >> 8], 1);
      }
    }
  } else {
#pragma unroll
    for (int j = 0; j < AITER; ++j) {
      const int i = tid + j * 256;
      if (i < ecnt) {
        const int   r = rows[e0 + i];
        const int   c = cols[e0 + i];
        const float w = ew[e0 + i];
        held[j].x = c | ((int)__half_as_ushort(__float2half_rn(w)) << 16);
        held[j].y = r;
        atomicAdd(&cnt[r >> 8], 1);
      }
    }
  }
  __syncthreads();

  sc[tid] = cnt[tid];
  __syncthreads();
  for (int o = 1; o < 256; o <<= 1) {
    int u = (tid >= o) ? sc[tid - o] : 0;
    __syncthreads();
    sc[tid] += u;
    __syncthreads();
  }
  offs[tid] = sc[tid] - cnt[tid];
  if (tid < K_BUCKETS && cnt[tid] > 0)
    gbase[tid] = atomicAdd(&gcursor[tid], cnt[tid]);
  __syncthreads();

#pragma unroll
  for (int j = 0; j < AITER; ++j) {
    if (full || (tid + j * 256) < ecnt) {
      const int b = held[j].y >> 8;
      const int p = offs[b] + atomicAdd(&cnt2[b], 1);
      buf[p] = held[j];
    }
  }
  __syncthreads();

  for (int i = tid; i < ecnt; i += 256) {
    const int2 v   = buf[i];
    const int  b   = v.y >> 8;
    const int  idx = gbase[b] + (i - offs[b]);
    if (idx < BCAP) ebuf[(long)b * BCAP + idx] = v;
  }
}

// ========================= partition phase B body (scan inlined) =========================
// smem carve: cnt[2048] | cur[2048] | sh[256] | sbase[1]  (17412 B)
__device__ void partB_body(const int b, char* smem,
                           const int* __restrict__ gcursor,
                           const int2* __restrict__ ebuf,
                           unsigned* __restrict__ se,
                           int* __restrict__ rowptr) {
  int* cnt = (int*)smem;
  int* cur = cnt + 256 * CG_N;
  int* sh  = cur + 256 * CG_N;
  int* sbp = sh + 256;
  const int tid = threadIdx.x;

  const int gv = (tid < K_BUCKETS) ? gcursor[tid] : 0;
  sh[tid] = gv;
  __syncthreads();
  for (int o = 1; o < 256; o <<= 1) {
    int u = (tid >= o) ? sh[tid - o] : 0;
    __syncthreads();
    sh[tid] += u;
    __syncthreads();
  }
  if (tid == b) *sbp = sh[tid] - gv;
  if (b == 0 && tid == 0) rowptr[N_NODES] = E_EDGES;

#pragma unroll
  for (int j = 0; j < CG_N; ++j) {
    cnt[tid * CG_N + j] = 0;
    cur[tid * CG_N + j] = 0;
  }
  __syncthreads();
  const int base = *sbp;
  const int cntb = min(gcursor[b], BCAP);

  const int2* __restrict__ src = ebuf + (long)b * BCAP;
  for (int i = tid; i < cntb; i += 256) {
    const int2 v = src[i];
    const int key = (v.y & 255) * CG_N + ((v.x & 0xFFFF) >> CG_SHIFT);
    atomicAdd(&cnt[key], 1);
  }
  __syncthreads();

  int loc[CG_N];
  int s = 0;
#pragma unroll
  for (int j = 0; j < CG_N; ++j) { loc[j] = s; s += cnt[tid * CG_N + j]; }
  sh[tid] = s;
  __syncthreads();
  for (int o = 1; o < 256; o <<= 1) {
    int u = (tid >= o) ? sh[tid - o] : 0;
    __syncthreads();
    sh[tid] += u;
    __syncthreads();
  }
  const int tb = sh[tid] - s;
#pragma unroll
  for (int j = 0; j < CG_N; ++j) cnt[tid * CG_N + j] = tb + loc[j];
  const int grow = b * 256 + tid;
  if (grow < N_NODES) rowptr[grow] = base + tb;
  __syncthreads();

  for (int i = tid; i < cntb; i += 256) {
    const int2 v   = src[i];
    const int  key = (v.y & 255) * CG_N + ((v.x & 0xFFFF) >> CG_SHIFT);
    const int  p   = cnt[key] + atomicAdd(&cur[key], 1);
    se[base + p] = (unsigned)v.x;
  }
}

// ========================= MFMA GEMM body =========================
// Hout = act(X) @ W ; X fp32 (layer 0) or fp16. OUT_FP8: fp8 e4m3 output.
// smem carve: Xs[64*PITCH f16] | Ws[FOUT_PAD*PITCH f16] | ssc[128] | ssh[128]
template <int FOUT, int FOUT_PAD, bool FUSE, bool OUT_FP8, typename XT>
__device__ __forceinline__ void gemm_body(const int bid, char* smem,
                                          const XT* __restrict__ X,
                                          const __half* __restrict__ Wt,
                                          void* __restrict__ Hout,
                                          const float* __restrict__ stats,
                                          const float* __restrict__ g,
                                          const float* __restrict__ be) {
  constexpr int CT    = FOUT_PAD / 16;
  constexpr int PITCH = 136;

  _Float16* Xs  = (_Float16*)smem;
  _Float16* Ws  = Xs + 64 * PITCH;
  float*    ssc = (float*)(Ws + FOUT_PAD * PITCH);
  float*    ssh = ssc + 128;

  const int tid  = threadIdx.x;
  const int row0 = bid * 64;

  if constexpr (FUSE) {
    if (tid < 128) {
      const float mean = stats[tid] * (1.0f / N_NODES);
      const float var  = stats[128 + tid] * (1.0f / N_NODES) - mean * mean;
      const float sc   = g[tid] * rsqrtf(var + BN_EPS);
      ssc[tid] = sc;
      ssh[tid] = be[tid] - mean * sc;
    }
    __syncthreads();
  }

  for (int i = tid; i < FOUT_PAD * 16; i += 256) {
    const int r  = i >> 4;
    const int c8 = (i & 15) * 8;
    *(f16x8*)(Ws + r * PITCH + c8) = *(const f16x8*)(Wt + r * 128 + c8);
  }

  if constexpr (sizeof(XT) == 4) {  // fp32 input (layer 0)
    for (int i = tid; i < 64 * 32; i += 256) {
      const int r  = i >> 5;
      const int k4 = (i & 31) * 4;
      const int gr = min(row0 + r, N_NODES - 1);
      float4 v = *(const float4*)((const float*)X + (long)gr * 128 + k4);
      _Float16* d = Xs + r * PITCH + k4;
      d[0] = (_Float16)v.x; d[1] = (_Float16)v.y;
      d[2] = (_Float16)v.z; d[3] = (_Float16)v.w;
    }
  } else {  // fp16 agg input
    for (int i = tid; i < 64 * 16; i += 256) {
      const int r  = i >> 4;
      const int k8 = (i & 15) * 8;
      const int gr = min(row0 + r, N_NODES - 1);
      f16x8 v = *(const f16x8*)((const _Float16*)X + (long)gr * 128 + k8);
      if constexpr (FUSE) {
#pragma unroll
        for (int j = 0; j < 8; ++j)
          v[j] = (_Float16)fmaxf((float)v[j] * ssc[k8 + j] + ssh[k8 + j], 0.f);
      }
      *(f16x8*)(Xs + r * PITCH + k8) = v;
    }
  }
  __syncthreads();

  const int wave = tid >> 6;
  const int lane = tid & 63;
  const int m    = lane & 15;
  const int q    = lane >> 4;
  const int rw   = wave * 16;

  f16x8 af[4];
  {
    const _Float16* ab = Xs + (rw + m) * PITCH + q * 8;
#pragma unroll
    for (int ks = 0; ks < 4; ++ks) af[ks] = *(const f16x8*)(ab + ks * 32);
  }

  f32x4 acc[CT];
#pragma unroll
  for (int ct = 0; ct < CT; ++ct) acc[ct] = (f32x4){0.f, 0.f, 0.f, 0.f};

#pragma unroll
  for (int ct = 0; ct < CT; ++ct) {
    const _Float16* bb = Ws + (ct * 16 + m) * PITCH + q * 8;
#pragma unroll
    for (int ks = 0; ks < 4; ++ks) {
      const f16x8 bf = *(const f16x8*)(bb + ks * 32);
      acc[ct] = __builtin_amdgcn_mfma_f32_16x16x32_f16(af[ks], bf, acc[ct], 0, 0, 0);
    }
  }

  __syncthreads();
#pragma unroll
  for (int ct = 0; ct < CT; ++ct) {
#pragma unroll
    for (int reg = 0; reg < 4; ++reg) {
      Xs[(rw + q * 4 + reg) * PITCH + ct * 16 + m] = (_Float16)acc[ct][reg];
    }
  }
  __syncthreads();

  if constexpr (OUT_FP8) {
    constexpr int C16 = FOUT / 16;  // 8
    unsigned char* H8 = (unsigned char*)Hout;
    for (int i = tid; i < 64 * C16; i += 256) {
      const int r   = i / C16;
      const int c16 = (i % C16) * 16;
      const int gr  = row0 + r;
      if (gr < N_NODES) {
        const _Float16* src = Xs + r * PITCH + c16;
        int w[4];
#pragma unroll
        for (int j = 0; j < 4; ++j) {
          int p = __builtin_amdgcn_cvt_pk_fp8_f32((float)src[4 * j + 0],
                                                  (float)src[4 * j + 1], 0, false);
          p = __builtin_amdgcn_cvt_pk_fp8_f32((float)src[4 * j + 2],
                                              (float)src[4 * j + 3], p, true);
          w[j] = p;
        }
        *(int4*)(H8 + (long)gr * FOUT + c16) = make_int4(w[0], w[1], w[2], w[3]);
      }
    }
  } else {
    constexpr int C8 = FOUT / 8;
    __half* H16 = (__half*)Hout;
    for (int i = tid; i < 64 * C8; i += 256) {
      const int r  = i / C8;
      const int c8 = (i % C8) * 8;
      const int gr = row0 + r;
      if (gr < N_NODES)
        *(f16x8*)(H16 + (long)gr * FOUT + c8) = *(const f16x8*)(Xs + r * PITCH + c8);
    }
  }
}

// ========================= merged partB + gemm0 kernel =========================
// blocks [0, K_BUCKETS): partB (CSR fine sort).  blocks [K_BUCKETS, +782):
// layer-0 GEMM (independent of CSR build) -> fills partB's idle CUs.
constexpr int SMEM_MERGED = (64 + 128) * 136 * 2 + 1024;  // 53248 B (gemm > partB 17KB)

__global__ __launch_bounds__(256) void partB_gemm0_ker(const int* __restrict__ gcursor,
                                                       const int2* __restrict__ ebuf,
                                                       unsigned* __restrict__ se,
                                                       int* __restrict__ rowptr,
                                                       const float* __restrict__ x,
                                                       const __half* __restrict__ wt0,
                                                       unsigned char* __restrict__ h) {
  __shared__ __align__(16) char smem[SMEM_MERGED];
  if (blockIdx.x < K_BUCKETS) {
    partB_body(blockIdx.x, smem, gcursor, ebuf, se, rowptr);
  } else {
    gemm_body<128, 128, false, true, float>(blockIdx.x - K_BUCKETS, smem,
                                            x, wt0, h, nullptr, nullptr, nullptr);
  }
}

// ========================= standalone GEMM kernel (layers 1/2) =========================
template <int FOUT, int FOUT_PAD, bool FUSE, bool OUT_FP8, typename XT>
__global__ __launch_bounds__(256) void gemm_mfma_ker(const XT* __restrict__ X,
                                                     const __half* __restrict__ Wt,
                                                     void* __restrict__ Hout,
                                                     const float* __restrict__ stats,
                                                     const float* __restrict__ g,
                                                     const float* __restrict__ be) {
  __shared__ __align__(16) char smem[(64 + FOUT_PAD) * 136 * 2 + 1024];
  gemm_body<FOUT, FOUT_PAD, FUSE, OUT_FP8, XT>(blockIdx.x, smem, X, Wt, Hout, stats, g, be);
}

// ========================= CSR SpMM (fp8 H, 1 row/wave, dual-edge) =========================
// Half-wave split: lanes 0-31 process edge e, lanes 32-63 edge e+1; each lane
// loads a dword (4 fp8 cols), so one gather instruction covers 2 edges (256B).
// Unroll-16 keeps 16 edges in flight. __shfl_xor(32) merges the halves.
__global__ __launch_bounds__(256) void spmm_fp8_ker(const int* __restrict__ rowptr,
                                                    const unsigned* __restrict__ se,
                                                    const unsigned char* __restrict__ H,
                                                    __half* __restrict__ A) {
  const int gid  = blockIdx.x * 256 + threadIdx.x;
  const int lane = threadIdx.x & 63;
  const int hsel = lane >> 5;           // 0: lanes 0-31, 1: lanes 32-63
  const int l32  = lane & 31;
  const int wid  = __builtin_amdgcn_readfirstlane(gid >> 6);
  if (wid >= N_NODES) return;
  const int beg = rowptr[wid];
  const int end = rowptr[wid + 1];
  const unsigned* __restrict__ Hl = (const unsigned*)H + l32;  // row stride 32 dwords
  float a0 = 0.f, a1 = 0.f, a2 = 0.f, a3 = 0.f;

#define PAIR(U0, U1)                                                            \
  {                                                                             \
    const unsigned u_  = hsel ? (U1) : (U0);                                    \
    const unsigned d_  = Hl[(u_ & 0xFFFF) * 32];                                \
    const float    w_  = dec_w(u_);                                             \
    const f32x2    lo_ = __builtin_amdgcn_cvt_pk_f32_fp8((int)d_, false);       \
    const f32x2    hi_ = __builtin_amdgcn_cvt_pk_f32_fp8((int)d_, true);        \
    a0 += w_ * lo_[0]; a1 += w_ * lo_[1];                                       \
    a2 += w_ * hi_[0]; a3 += w_ * hi_[1];                                       \
  }

  int e = beg;
  {
    const int head = min(end - e, (4 - (e & 3)) & 3);
    for (int i = 0; i < head; i += 2) {
      const unsigned u0 = se[e + i];
      const unsigned u1 = (i + 1 < head) ? se[e + i + 1] : 0u;  // w=0 -> no-op
      PAIR(u0, u1)
    }
    e += head;
  }
  for (; e + 16 <= end; e += 16) {
    const uint4 a = *(const uint4*)(se + e);
    const uint4 b = *(const uint4*)(se + e + 4);
    const uint4 c = *(const uint4*)(se + e + 8);
    const uint4 d = *(const uint4*)(se + e + 12);
    PAIR(a.x, a.y) PAIR(a.z, a.w) PAIR(b.x, b.y) PAIR(b.z, b.w)
    PAIR(c.x, c.y) PAIR(c.z, c.w) PAIR(d.x, d.y) PAIR(d.z, d.w)
  }
  for (; e + 4 <= end; e += 4) {
    const uint4 a = *(const uint4*)(se + e);
    PAIR(a.x, a.y) PAIR(a.z, a.w)
  }
  for (; e < end; e += 2) {
    const unsigned u0 = se[e];
    const unsigned u1 = (e + 1 < end) ? se[e + 1] : 0u;
    PAIR(u0, u1)
  }
#undef PAIR

  a0 += __shfl_xor(a0, 32, 64);
  a1 += __shfl_xor(a1, 32, 64);
  a2 += __shfl_xor(a2, 32, 64);
  a3 += __shfl_xor(a3, 32, 64);

  if (lane < 32) {
    const __half2 h01 = __floats2half2_rn(a0, a1);
    const __half2 h23 = __floats2half2_rn(a2, a3);
    uint2 st;
    st.x = *(const unsigned*)&h01;
    st.y = *(const unsigned*)&h23;
    *(uint2*)((__half*)A + (long)wid * 128 + l32 * 4) = st;
  }
}

// ========================= CSR SpMM F=40 (fp16 H) + bias, 20-lane teams =========================
// 12 row-teams of 20 lanes per 256-thread block (240/256 active). Each lane
// loads __half2 (dword, 2 cols): half the gather lanes of the 40-lane scheme
// at 2x width, 2x rows/block (4167 blocks, was 8334). Per-column edge sum
// order unchanged -> bitwise-identical output.
__global__ __launch_bounds__(256) void spmm_csr40_ker(const int* __restrict__ rowptr,
                                                      const unsigned* __restrict__ se,
                                                      const __half* __restrict__ H,
                                                      const float* __restrict__ b,
                                                      float* __restrict__ out) {
  const int t    = threadIdx.x;
  const int team = t / 20;
  const int l    = t % 20;             // col-pair index 0..19
  if (team >= TEAMS20) return;
  const int wid = blockIdx.x * TEAMS20 + team;
  if (wid >= N_NODES) return;
  const int beg = rowptr[wid];
  const int end = rowptr[wid + 1];
  const unsigned* __restrict__ Hd = (const unsigned*)H;  // row stride 20 dwords
  float a0 = 0.f, a1 = 0.f;

#define F40_EDGE(U)                                                            \
  {                                                                            \
    const unsigned u_ = (U);                                                   \
    const unsigned d_ = Hd[(u_ & 0xFFFF) * 20u + l];                           \
    const float    w_ = dec_w(u_);                                             \
    const float2   f_ = __half22float2(*(const __half2*)&d_);                  \
    a0 += w_ * f_.x; a1 += w_ * f_.y;                                          \
  }

  int e = beg;
  for (; e < end && (e & 3); ++e) F40_EDGE(se[e]);
  for (; e + 8 <= end; e += 8) {
    const uint4 a = *(const uint4*)(se + e);
    const uint4 c = *(const uint4*)(se + e + 4);
    F40_EDGE(a.x) F40_EDGE(a.y) F40_EDGE(a.z) F40_EDGE(a.w)
    F40_EDGE(c.x) F40_EDGE(c.y) F40_EDGE(c.z) F40_EDGE(c.w)
  }
  for (; e + 4 <= end; e += 4) {
    const uint4 a = *(const uint4*)(se + e);
    F40_EDGE(a.x) F40_EDGE(a.y) F40_EDGE(a.z) F40_EDGE(a.w)
  }
  for (; e < end; ++e) F40_EDGE(se[e]);
#undef F40_EDGE

  const float2 bb = *(const float2*)(b + l * 2);
  float2 r;
  r.x = a0 + bb.x;
  r.y = a1 + bb.y;
  *(float2*)(out + (long)wid * 40 + l * 2) = r;
}

// ========================= BatchNorm stats (fp16 input) =========================
// half2 loads (thread owns a col pair, 4-row stride), LDS block reduce,
// 128 global atomics per block (131K total, half of the per-thread scheme).
constexpr int BN_BLOCKS   = 512;
constexpr int BN_ROWS_PER = (N_NODES + BN_BLOCKS - 1) / BN_BLOCKS;  // 98

__global__ __launch_bounds__(256) void bn_stats_ker(const __half* __restrict__ A,
                                                    float* __restrict__ stats) {
  __shared__ float s_sh[128], q_sh[128];
  const int tid = threadIdx.x;
  if (tid < 128) { s_sh[tid] = 0.f; q_sh[tid] = 0.f; }
  __syncthreads();

  const int c2 = (tid & 63) * 2;
  const int rs = tid >> 6;  // 0..3
  const int r0 = blockIdx.x * BN_ROWS_PER;
  const int re = min(r0 + BN_ROWS_PER, N_NODES);
  float s0 = 0.f, s1 = 0.f, q0 = 0.f, q1 = 0.f;
  for (int r = r0 + rs; r < re; r += 4) {
    const float2 v = __half22float2(*(const __half2*)(A + (long)r * 128 + c2));
    s0 += v.x; q0 += v.x * v.x;
    s1 += v.y; q1 += v.y * v.y;
  }
  atomicAdd(&s_sh[c2 + 0], s0);
  atomicAdd(&s_sh[c2 + 1], s1);
  atomicAdd(&q_sh[c2 + 0], q0);
  atomicAdd(&q_sh[c2 + 1], q1);
  __syncthreads();
  if (tid < 128) {
    atomicAdd(&stats[tid],       s_sh[tid]);
    atomicAdd(&stats[128 + tid], q_sh[tid]);
  }
}

// ---------------------------------------------------------------------------
extern "C" void kernel_launch(void* const* d_in, const int* in_sizes, int n_in,
                              void* d_out, int out_size, void* d_ws, size_t ws_size,
                              hipStream_t stream) {
  const float* x    = (const float*)d_in[0];
  const int*   erow = (const int*)d_in[1];
  const int*   ecol = (const int*)d_in[2];
  const float* ew   = (const float*)d_in[3];
  const float* W0   = (const float*)d_in[4];
  const float* g0   = (const float*)d_in[6];
  const float* be0  = (const float*)d_in[7];
  const float* W1   = (const float*)d_in[8];
  const float* g1   = (const float*)d_in[10];
  const float* be1  = (const float*)d_in[11];
  const float* W2   = (const float*)d_in[12];
  const float* b2   = (const float*)d_in[13];
  float* out = (float*)d_out;

  // workspace layout (16B-aligned sections)
  unsigned char* h  = (unsigned char*)d_ws;                  // N*128 fp8 / N*40 fp16
  __half*   agg     = (__half*)(h + (long)N_NODES * 256);    // N*128 fp16
  float*    stats0  = (float*)(agg + (long)N_NODES * 128);   // 256
  float*    stats1  = stats0 + 256;                          // 256
  int*      gcursor = (int*)(stats1 + 256);                  // 256
  int*      rowptr  = gcursor + 256;                         // N+1 (pad 50004)
  unsigned* se      = (unsigned*)(rowptr + 50004);           // E (16B-aligned)
  int2*     ebuf    = (int2*)(se + E_EDGES);                 // K*BCAP
  __half*   wt0     = (__half*)(ebuf + (long)K_BUCKETS * BCAP);  // 128*128
  __half*   wt1     = wt0 + 128 * 128;                       // 128*128
  __half*   wt2     = wt1 + 128 * 128;                       // 48*128

  const int g_gemm   = (N_NODES + 63) / 64;                // 782
  const int g_spmm   = (N_NODES * 64) / 256;               // 12500
  const int g_spmm40 = (N_NODES + TEAMS20 - 1) / TEAMS20;  // 4167

  // ---- zero stats0 | stats1 | gcursor (contiguous 768 floats) ----
  (void)hipMemsetAsync(stats0, 0, 768 * sizeof(float), stream);

  // ---- CSR phase A + W transposes (independent work, one launch) ----
  partA_prep_ker<<<PART_BLK + PREP_BLK, 256, 0, stream>>>(
      erow, ecol, ew, gcursor, ebuf, W0, W1, W2, wt0, wt1, wt2);

  // ---- CSR phase B (196 blocks) co-scheduled with layer-0 GEMM (782) ----
  partB_gemm0_ker<<<K_BUCKETS + g_gemm, 256, 0, stream>>>(
      gcursor, ebuf, se, rowptr, x, wt0, h);

  // ---- layer 0 aggregate (H fp8) ----
  spmm_fp8_ker<<<g_spmm, 256, 0, stream>>>(rowptr, se, h, agg);
  bn_stats_ker<<<BN_BLOCKS, 256, 0, stream>>>(agg, stats0);

  // ---- layer 1 (BN0 fused into GEMM staging; H fp8) ----
  gemm_mfma_ker<128, 128, true, true, _Float16><<<g_gemm, 256, 0, stream>>>(
      (const _Float16*)agg, wt1, h, stats0, g0, be0);
  spmm_fp8_ker<<<g_spmm, 256, 0, stream>>>(rowptr, se, h, agg);
  bn_stats_ker<<<BN_BLOCKS, 256, 0, stream>>>(agg, stats1);

  // ---- layer 2 (BN1 fused into GEMM; H fp16; bias b2 fused into SpMM) ----
  gemm_mfma_ker<40, 48, true, false, _Float16><<<g_gemm, 256, 0, stream>>>(
      (const _Float16*)agg, wt2, h, stats1, g1, be1);
  spmm_csr40_ker<<<g_spmm40, 256, 0, stream>>>(rowptr, se, (const __half*)h, b2, out);
}